// Round 3
// baseline (1377.022 us; speedup 1.0000x reference)
//
#include <hip/hip_runtime.h>
#include <hip/hip_bf16.h>

#define N_CTX 4096
#define DM    2048

typedef __attribute__((ext_vector_type(8))) short short8;
typedef __attribute__((ext_vector_type(4))) float f32x4;
typedef unsigned short ushort_t;

#define SBAR() __builtin_amdgcn_sched_barrier(0)
#define WBAR() __builtin_amdgcn_s_barrier()

__device__ __forceinline__ ushort_t f2bf(float x) {
    __hip_bfloat16 h = __float2bfloat16(x);
    return __builtin_bit_cast(ushort_t, h);
}
__device__ __forceinline__ float bf2f(ushort_t u) {
    return __bfloat162float(__builtin_bit_cast(__hip_bfloat16, u));
}

__device__ __forceinline__ void gload16(const void* g, void* l) {
    __builtin_amdgcn_global_load_lds((const __attribute__((address_space(1))) void*)g,
                                     (__attribute__((address_space(3))) void*)l,
                                     16, 0, 0);
}

// ---------------- cast kernels ----------------

__global__ __launch_bounds__(256) void split_cast_kernel(
    const float* __restrict__ in, ushort_t* __restrict__ hi, ushort_t* __restrict__ lo, int n4)
{
    int idx = blockIdx.x * 256 + threadIdx.x;
    if (idx >= n4) return;
    float4 v = reinterpret_cast<const float4*>(in)[idx];
    float vv[4] = {v.x, v.y, v.z, v.w};
    ushort_t h[4], l[4];
#pragma unroll
    for (int j = 0; j < 4; ++j) {
        h[j] = f2bf(vv[j]);
        l[j] = f2bf(vv[j] - bf2f(h[j]));
    }
    reinterpret_cast<ushort4*>(hi)[idx] = *reinterpret_cast<ushort4*>(h);
    reinterpret_cast<ushort4*>(lo)[idx] = *reinterpret_cast<ushort4*>(l);
}

template <bool SPLIT>
__global__ __launch_bounds__(256) void transpose_cast_kernel(
    const float* __restrict__ in, ushort_t* __restrict__ hi, ushort_t* __restrict__ lo,
    int R, int C)
{
    __shared__ float tile[32][33];
    int bc = blockIdx.x * 32;
    int br = blockIdx.y * 32;
    int tx = threadIdx.x, ty = threadIdx.y;   // (32, 8)
#pragma unroll
    for (int r = ty; r < 32; r += 8)
        tile[r][tx] = in[(size_t)(br + r) * C + bc + tx];
    __syncthreads();
#pragma unroll
    for (int c = ty; c < 32; c += 8) {
        float v = tile[tx][c];
        size_t o = (size_t)(bc + c) * R + br + tx;
        ushort_t h = f2bf(v);
        hi[o] = h;
        if (SPLIT) lo[o] = f2bf(v - bf2f(h));
    }
}

// ---------------- 8-phase 256x128 GEMM ----------------
// C[M][N] = sum_p A_p @ B_p^T ; A_p: [M][K] bf16 row-major, B_p: [N][K] bf16.
// BM=256, BN=128, BK=64. 8 waves (4M x 2N), per-wave 64x64 output.
// LDS: Abuf[2] 32KB each @0/32K, Bbuf[2] 16KB each @64K/80K = 96KB.
// Per K-tile: phases {P1: rd A01+B01, mfma q(0,0)} {P2: rd B23, q(0,1)}
// {P3: rd A23, q(1,1)} {P4: stage next-next tile (6 gload_lds), vmcnt(6), q(1,0)}.
// vmcnt(6) at P4/P8 only (counted, never 0 in-loop).
// OM: 0=f32 out, 1=bf16 out, 2=split bf16 out. CAUSAL: skip blocks above diag.
// CKLIM: limit K to (by+1)*256 (A columns beyond are zero — causal attn rows).

template <int NP, int OM, bool CAUSAL, bool CKLIM>
__global__ __launch_bounds__(512, 2) void gemm8_kernel(
    const ushort_t* __restrict__ A0, const ushort_t* __restrict__ B0,
    const ushort_t* __restrict__ A1, const ushort_t* __restrict__ B1,
    const ushort_t* __restrict__ A2, const ushort_t* __restrict__ B2,
    int K, int kshift, int nbxs, int ldc,
    float* __restrict__ Cf, ushort_t* __restrict__ Ch, ushort_t* __restrict__ Cl)
{
    extern __shared__ char lds[];

    // bijective XCD swizzle (grids are multiples of 8): contiguous wgid chunk per XCD
    const int nwg = gridDim.x;
    const int q8 = nwg >> 3;
    const int wgid = (blockIdx.x & 7) * q8 + (blockIdx.x >> 3);
    const int by = wgid >> nbxs;
    const int bx = wgid & ((1 << nbxs) - 1);
    if (CAUSAL && bx * 128 > by * 256 + 255) return;

    const int t = threadIdx.x;
    const int l = t & 63;
    const int w = t >> 6;
    const int wr = w >> 1;          // 0..3 -> 64-row band
    const int wc = w & 1;           // 0..1 -> 64-col band
    const int lr = l & 15;
    const int lc = l >> 4;

    const size_t arow0 = (size_t)by * 256;
    const size_t brow0 = (size_t)bx * 128;

    int ntiles = (NP * K) >> 6;
    if (CKLIM) { int lim = (by + 1) * 4; if (lim < ntiles) ntiles = lim; }
    const int kmask = (K >> 6) - 1;   // per-pair K-tiles - 1 (power of 2)

    f32x4 acc[4][4];
#pragma unroll
    for (int m = 0; m < 4; ++m)
#pragma unroll
        for (int n = 0; n < 4; ++n) acc[m][n] = (f32x4){0.f, 0.f, 0.f, 0.f};

    auto stage = [&](int T, int buf) {
        int p = (NP > 1) ? (T >> kshift) : 0;
        int kt = (T & kmask) << 6;
        const ushort_t* Ap = A0; const ushort_t* Bp = B0;
        if (NP > 1 && p == 1) { Ap = A1; Bp = B1; }
        if (NP > 2 && p == 2) { Ap = A2; Bp = B2; }
        char* ab = lds + buf * 32768;
#pragma unroll
        for (int i = 0; i < 4; ++i) {
            int f = i * 512 + t;
            int row = f >> 3, c = f & 7;
            gload16(Ap + (arow0 + row) * (size_t)K + kt + ((c ^ (row & 7)) << 3),
                    ab + f * 16);
        }
        char* bb = lds + 65536 + buf * 16384;
#pragma unroll
        for (int i = 0; i < 2; ++i) {
            int f = i * 512 + t;
            int row = f >> 3, c = f & 7;
            gload16(Bp + (brow0 + row) * (size_t)K + kt + ((c ^ (row & 7)) << 3),
                    bb + f * 16);
        }
    };

    auto rdA = [&](short8* d, int mb, int buf) {
        const char* base = lds + buf * 32768;
#pragma unroll
        for (int mi = 0; mi < 2; ++mi)
#pragma unroll
            for (int kk = 0; kk < 2; ++kk) {
                int row = wr * 64 + (mb + mi) * 16 + lr;
                d[mi * 2 + kk] = *(const short8*)(base + row * 128 +
                                  ((((kk << 2) + lc) ^ (lr & 7)) << 4));
            }
    };
    auto rdB = [&](short8* d, int nb, int buf) {
        const char* base = lds + 65536 + buf * 16384;
#pragma unroll
        for (int ni = 0; ni < 2; ++ni)
#pragma unroll
            for (int kk = 0; kk < 2; ++kk) {
                int row = wc * 64 + (nb + ni) * 16 + lr;
                d[ni * 2 + kk] = *(const short8*)(base + row * 128 +
                                  ((((kk << 2) + lc) ^ (lr & 7)) << 4));
            }
    };
    auto mm8 = [&](const short8* a, const short8* b, int mb, int nb) {
#pragma unroll
        for (int mi = 0; mi < 2; ++mi)
#pragma unroll
            for (int ni = 0; ni < 2; ++ni)
#pragma unroll
                for (int kk = 0; kk < 2; ++kk)
                    acc[mb + mi][nb + ni] = __builtin_amdgcn_mfma_f32_16x16x32_bf16(
                        a[mi * 2 + kk], b[ni * 2 + kk], acc[mb + mi][nb + ni], 0, 0, 0);
    };

    // prologue: stage tiles 0,1; wait tile 0 (6 loads of tile 1 remain in flight)
    stage(0, 0);
    stage(ntiles > 1 ? 1 : 0, 1);
    asm volatile("s_waitcnt vmcnt(6)" ::: "memory");
    SBAR(); WBAR(); SBAR();

    const int nit = ntiles >> 1;   // ntiles always even here
    for (int it = 0; it < nit; ++it) {
        int T2 = 2 * it + 2; if (T2 > ntiles - 1) T2 = ntiles - 1;
        int T3 = 2 * it + 3; if (T3 > ntiles - 1) T3 = ntiles - 1;
#pragma unroll
        for (int h = 0; h < 2; ++h) {
            const int buf = h;
            const int Tp = h ? T3 : T2;
            short8 a01[4], a23[4], b01[4], b23[4];
            // P1
            rdA(a01, 0, buf); rdB(b01, 0, buf);
            SBAR(); WBAR(); SBAR();
            __builtin_amdgcn_s_setprio(1); mm8(a01, b01, 0, 0); __builtin_amdgcn_s_setprio(0);
            SBAR(); WBAR(); SBAR();
            // P2
            rdB(b23, 2, buf);
            SBAR(); WBAR(); SBAR();
            __builtin_amdgcn_s_setprio(1); mm8(a01, b23, 0, 2); __builtin_amdgcn_s_setprio(0);
            SBAR(); WBAR(); SBAR();
            // P3
            rdA(a23, 2, buf);
            SBAR(); WBAR(); SBAR();
            __builtin_amdgcn_s_setprio(1); mm8(a23, b23, 2, 2); __builtin_amdgcn_s_setprio(0);
            SBAR(); WBAR(); SBAR();
            // P4: prefetch tile Tp into this buf (reads of it finished in P1-P3)
            stage(Tp, buf);
            asm volatile("s_waitcnt vmcnt(6)" ::: "memory");
            SBAR(); WBAR(); SBAR();
            __builtin_amdgcn_s_setprio(1); mm8(a23, b01, 2, 0); __builtin_amdgcn_s_setprio(0);
            SBAR(); WBAR(); SBAR();
        }
    }

    // epilogue: C/D layout col = lane&15, row = (lane>>4)*4 + reg
    const int r0 = by * 256 + wr * 64 + (lc << 2);
    const int c0 = bx * 128 + wc * 64 + lr;
#pragma unroll
    for (int m = 0; m < 4; ++m)
#pragma unroll
        for (int n = 0; n < 4; ++n)
#pragma unroll
            for (int j = 0; j < 4; ++j) {
                size_t o = (size_t)(r0 + m * 16 + j) * ldc + (c0 + n * 16);
                float v = acc[m][n][j];
                if (OM == 0) {
                    Cf[o] = v;
                } else if (OM == 1) {
                    Ch[o] = f2bf(v);
                } else {
                    ushort_t hh = f2bf(v);
                    Ch[o] = hh;
                    Cl[o] = f2bf(v - bf2f(hh));
                }
            }
}

// ---------------- causal row softmax ----------------

__device__ __forceinline__ float waveMax(float v) {
#pragma unroll
    for (int o = 32; o > 0; o >>= 1) v = fmaxf(v, __shfl_xor(v, o, 64));
    return v;
}
__device__ __forceinline__ float waveSum(float v) {
#pragma unroll
    for (int o = 32; o > 0; o >>= 1) v += __shfl_xor(v, o, 64);
    return v;
}

__global__ __launch_bounds__(256) void softmax_kernel(
    const float* __restrict__ S, ushort_t* __restrict__ A)
{
    const int i = blockIdx.x;
    __shared__ float row[N_CTX];
    __shared__ float red[8];
    const int t = threadIdx.x;
    const int len = i + 1;
    const float* Srow = S + (size_t)i * N_CTX;

    float m = -3.4e38f;
    for (int j = t; j < len; j += 256) {
        float v = Srow[j];
        row[j] = v;
        m = fmaxf(m, v);
    }
    m = waveMax(m);
    if ((t & 63) == 0) red[t >> 6] = m;
    __syncthreads();
    m = fmaxf(fmaxf(red[0], red[1]), fmaxf(red[2], red[3]));

    float s = 0.f;
    for (int j = t; j < len; j += 256) {
        float e = __expf(row[j] - m);
        row[j] = e;
        s += e;
    }
    s = waveSum(s);
    __syncthreads();
    if ((t & 63) == 0) red[t >> 6] = s;
    __syncthreads();
    float inv = 1.f / (red[0] + red[1] + red[2] + red[3]);

    ushort_t* Arow = A + (size_t)i * N_CTX;
    for (int j = t; j < N_CTX; j += 256)
        Arow[j] = (j < len) ? f2bf(row[j] * inv) : (ushort_t)0;
}

// ---------------- launcher ----------------

extern "C" void kernel_launch(void* const* d_in, const int* in_sizes, int n_in,
                              void* d_out, int out_size, void* d_ws, size_t ws_size,
                              hipStream_t stream)
{
    const float* E  = (const float*)d_in[0];
    const float* qk = (const float*)d_in[1];
    const float* ov = (const float*)d_in[2];
    float* out = (float*)d_out;

    char* ws = (char*)d_ws;
    size_t off = 0;
    auto take = [&](size_t bytes) -> char* {
        char* p = ws + off;
        off += (bytes + 255) & ~(size_t)255;
        return p;
    };

    ushort_t* Ehi   = (ushort_t*)take((size_t)N_CTX * DM * 2);
    ushort_t* Elo   = (ushort_t*)take((size_t)N_CTX * DM * 2);
    ushort_t* Et    = (ushort_t*)take((size_t)N_CTX * DM * 2);
    ushort_t* QKthi = (ushort_t*)take((size_t)DM * DM * 2);
    ushort_t* QKtlo = (ushort_t*)take((size_t)DM * DM * 2);
    ushort_t* OVt   = (ushort_t*)take((size_t)DM * DM * 2);
    ushort_t* Qhi   = (ushort_t*)take((size_t)N_CTX * DM * 2);
    ushort_t* Qlo   = (ushort_t*)take((size_t)N_CTX * DM * 2);
    float*    S     = (float*)take((size_t)N_CTX * N_CTX * 4);
    ushort_t* Attn  = (ushort_t*)take((size_t)N_CTX * N_CTX * 2);
    ushort_t* Hbf   = (ushort_t*)take((size_t)N_CTX * DM * 2);
    (void)ws_size; (void)in_sizes; (void)n_in; (void)out_size;

    constexpr int SMEM = 96 * 1024;
    // defensive: allow >64KB dynamic LDS (harmless if redundant)
    hipFuncSetAttribute((const void*)&gemm8_kernel<3, 2, false, false>,
                        hipFuncAttributeMaxDynamicSharedMemorySize, SMEM);
    hipFuncSetAttribute((const void*)&gemm8_kernel<3, 0, true, false>,
                        hipFuncAttributeMaxDynamicSharedMemorySize, SMEM);
    hipFuncSetAttribute((const void*)&gemm8_kernel<1, 1, false, true>,
                        hipFuncAttributeMaxDynamicSharedMemorySize, SMEM);
    hipFuncSetAttribute((const void*)&gemm8_kernel<1, 0, false, false>,
                        hipFuncAttributeMaxDynamicSharedMemorySize, SMEM);

    // 1. casts
    split_cast_kernel<<<dim3((N_CTX * DM / 4) / 256), 256, 0, stream>>>(E, Ehi, Elo, N_CTX * DM / 4);
    transpose_cast_kernel<true ><<<dim3(DM / 32, DM / 32),    dim3(32, 8), 0, stream>>>(qk, QKthi, QKtlo, DM, DM);
    transpose_cast_kernel<false><<<dim3(DM / 32, DM / 32),    dim3(32, 8), 0, stream>>>(ov, OVt, nullptr, DM, DM);
    transpose_cast_kernel<false><<<dim3(DM / 32, N_CTX / 32), dim3(32, 8), 0, stream>>>(E, Et, nullptr, N_CTX, DM);

    // 2. Q = E @ qk (3-pair split, split bf16 out). grid 16x16=256
    gemm8_kernel<3, 2, false, false><<<256, 512, SMEM, stream>>>(
        Ehi, QKthi, Ehi, QKtlo, Elo, QKthi, DM, 5, 4, DM, nullptr, Qhi, Qlo);

    // 3. S = Q @ E^T (3-pair split, causal, f32 out). grid 16x32=512
    gemm8_kernel<3, 0, true, false><<<512, 512, SMEM, stream>>>(
        Qhi, Ehi, Qhi, Elo, Qlo, Ehi, DM, 5, 5, N_CTX, S, nullptr, nullptr);

    // 4. attn = causal softmax(S)
    softmax_kernel<<<N_CTX, 256, 0, stream>>>(S, Attn);

    // 5. H = attn @ E (bf16 out, causal K-limit). grid 16x16=256
    gemm8_kernel<1, 1, false, true><<<256, 512, SMEM, stream>>>(
        Attn, Et, nullptr, nullptr, nullptr, nullptr, N_CTX, 6, 4, DM, nullptr, Hbf, nullptr);

    // 6. out = H @ ov (f32 out). grid 16x16=256
    gemm8_kernel<1, 0, false, false><<<256, 512, SMEM, stream>>>(
        Hbf, OVt, nullptr, nullptr, nullptr, nullptr, DM, 5, 4, DM, out, nullptr, nullptr);
}